// Round 18
// baseline (329.298 us; speedup 1.0000x reference)
//
#include <hip/hip_runtime.h>
#include <hip/hip_bf16.h>

typedef __hip_bfloat16 bf16;
typedef __attribute__((ext_vector_type(4))) float f32x4;
typedef __attribute__((ext_vector_type(8))) short s16x8;

#define N_TOK 4096   // B*S
#define Dm    512
#define Fm    2048
#define Em    8

__device__ __forceinline__ float bf2f(bf16 v) { return __bfloat162float(v); }
__device__ __forceinline__ bf16  f2bf(float f) { return __float2bfloat16(f); }

// async global->LDS, 16B per lane; LDS dest is wave-uniform base + lane*16
#define GL16(g, l)                                                              \
  __builtin_amdgcn_global_load_lds(                                             \
      (const __attribute__((address_space(1))) void*)(g),                       \
      (__attribute__((address_space(3))) void*)(l), 16, 0, 0)

// raw barrier (no implicit vmcnt drain) + compiler reorder fence
#define RBAR()                                  \
  do {                                          \
    __builtin_amdgcn_s_barrier();               \
    asm volatile("" ::: "memory");              \
  } while (0)

// ---- fused convert: x (2048 blks) + 4 DxD weights (1024 blks) + bkv (1) ----
__global__ void cvt_all(const float* __restrict__ x, const float* __restrict__ Wq,
                        const float* __restrict__ Wk, const float* __restrict__ Wv,
                        const float* __restrict__ Wo, const float* __restrict__ bk,
                        const float* __restrict__ bv, bf16* __restrict__ xb,
                        bf16* __restrict__ qw, bf16* __restrict__ kvw,
                        bf16* __restrict__ ow, float* __restrict__ bkv) {
  int b = blockIdx.x;
  if (b < 2048) {  // x: 4096*512/4 = 524288 float4
    int i = b * 256 + threadIdx.x;
    float4 v = reinterpret_cast<const float4*>(x)[i];
    bf16 tmp[4] = {f2bf(v.x), f2bf(v.y), f2bf(v.z), f2bf(v.w)};
    __builtin_memcpy(xb + (size_t)i * 4, tmp, 8);
  } else if (b < 3072) {
    int bb = b - 2048;
    int which = bb >> 8;
    int i = (bb & 255) * 256 + threadIdx.x;  // 65536 float4 per matrix
    const float* src = which == 0 ? Wq : which == 1 ? Wk : which == 2 ? Wv : Wo;
    bf16* dst = which == 0 ? qw : which == 1 ? kvw
              : which == 2 ? (kvw + (size_t)Dm * Dm) : ow;
    float4 v = reinterpret_cast<const float4*>(src)[i];
    bf16 tmp[4] = {f2bf(v.x), f2bf(v.y), f2bf(v.z), f2bf(v.w)};
    __builtin_memcpy(dst + (size_t)i * 4, tmp, 8);
  } else {
    for (int j = threadIdx.x; j < Dm; j += 256) {
      bkv[j] = bk[j];
      bkv[Dm + j] = bv[j];
    }
  }
}

// ------ fp32 [R][C] -> bf16 [C][R] transpose-convert, packed 8B stores -------
__global__ void transpose_cvt(const float* __restrict__ in, bf16* __restrict__ out,
                              int R, int C, long inb, long outb) {
  in  += (long)blockIdx.z * inb;
  out += (long)blockIdx.z * outb;
  __shared__ float t[32][33];
  int tid = threadIdx.x;
  int col = tid & 31, row8 = tid >> 5;
  int c0 = blockIdx.x * 32, r0 = blockIdx.y * 32;
#pragma unroll
  for (int i = 0; i < 4; ++i)
    t[row8 + i * 8][col] = in[(long)(r0 + row8 + i * 8) * C + c0 + col];
  __syncthreads();
  int cc = tid >> 3, rb = (tid & 7) * 4;  // out[c0+cc][r0+rb .. +4]
  bf16 tmp[4];
#pragma unroll
  for (int k = 0; k < 4; ++k) tmp[k] = f2bf(t[rb + k][cc]);
  __builtin_memcpy(out + (long)(c0 + cc) * R + r0 + rb, tmp, 8);
}

// == 128x128 BK=32 bf16 GEMM: lockstep 2-barrier + dbuf + COUNTED vmcnt (r18) ==
// C = A @ Bt^T (+bias[, relu]).  A:[M][K] lda, Bt:[N][K] ldb, C row-major ldc.
// The last untested cell in the structure matrix: keep the champion's 2-barrier
// LOCKSTEP skeleton (the property all fast variants share) but replace the
// per-iter vmcnt(0) drain (r1/r10: full L2/HBM latency exposed every K-iter)
// with a counted wait on a double buffer:
//   RBAR#1 (raw, no drain)  <- all waves done reading buf(t-1); safe to
//                              overwrite buf((t+1)&1) == buf((t-1)&1)
//   stage(t+1) -> buf^1     <- 4 gload_lds, stay in flight across compute(t)
//   s_waitcnt vmcnt(4)      <- retires exactly tile-t's 4 loads (in-order
//                              retirement, m135), issued ONE FULL ITER ago ->
//                              latency covered by compute(t-1). Never 0 in
//                              the main loop (T4); 0 only at the tail.
//   RBAR#2                  <- joins: ALL waves' t-loads retired & visible
//   ds_read (swizzled) + 16 MFMA (setprio)
// Hazards audited per-wave: ds_reads of buf(t-1) complete before their MFMAs
// (compiler lgkmcnt), which precede RBAR#1 in program order; asm memory
// clobbers pin builtin/asm ordering. LDS 2x16KB = 32KB -> 4 blocks/CU kept
// (r1 BK=32 == r10 BK=64 at 103us, so BK choice is free).
// Swizzle both sides (#21; 0 conflicts PMC-verified r13/r14 at BK=32):
// stage source chunk (lane&3)^((r>>1)&3), LDS linear; ds_read slot
// q^((r>>1)&3). Swapped MFMA operands (verified r8+): acc[m][n][r] ->
// C[bm+wm*64+m*16+la][bn+wn*64+n*16+q*4+r] -> packed 8B/16B stores.
template <bool RELU, bool OUT_BF16>
__global__ __launch_bounds__(256, 4) void gemm128p(
    const bf16* __restrict__ A, const bf16* __restrict__ Bt, void* __restrict__ Cout,
    const float* __restrict__ bias, int K, int lda, int ldb, int ldc,
    long abs_, long bbs, long cbs, long biasbs,
    const int* __restrict__ eid, int eid_scale) {
  __shared__ bf16 As[2][128 * 32];
  __shared__ bf16 Bs[2][128 * 32];

  int e  = blockIdx.z;
  int bm = blockIdx.x * 128, bn = blockIdx.y * 128;

  A    += (long)e * abs_;
  Bt   += (long)e * bbs;
  bias += (long)e * biasbs;
  long coff = (long)e * cbs;
  if (eid) A += (long)(*eid) * eid_scale;

  int tid = threadIdx.x, wv = tid >> 6, lane = tid & 63;
  int wm = wv >> 1, wn = wv & 1;
  int la = lane & 15, q = lane >> 4;
  int srow = lane >> 2;

  const bf16* Ab = A + (long)bm * lda;
  const bf16* Bb = Bt + (long)bn * ldb;
  int nt = K >> 5;  // BK = 32

  auto stage = [&](int t) {
    if (t >= nt) return;
    int k0 = t << 5;
    bf16* abuf = &As[t & 1][0];
    bf16* bbuf = &Bs[t & 1][0];
#pragma unroll
    for (int i = 0; i < 2; ++i) {
      int r = wv * 32 + i * 16 + srow;
      int c = (lane & 3) ^ ((r >> 1) & 3);  // inverse-swizzled source chunk
      GL16(Ab + (long)r * lda + k0 + c * 8, abuf + (wv * 32 + i * 16) * 32);
      GL16(Bb + (long)r * ldb + k0 + c * 8, bbuf + (wv * 32 + i * 16) * 32);
    }
  };

  f32x4 acc[4][4] = {};

  stage(0);  // prologue: tile 0 in flight

  for (int t = 0; t < nt; ++t) {
    RBAR();        // #1: all waves done reading buf(t-1) -> overwrite safe
    stage(t + 1);  // into buf((t+1)&1); stays in flight across compute(t)
    if (t + 1 < nt) asm volatile("s_waitcnt vmcnt(4)" ::: "memory");
    else            asm volatile("s_waitcnt vmcnt(0)" ::: "memory");
    RBAR();        // #2: every wave's tile-t loads retired -> buf(t) visible

    const bf16* Abuf = &As[t & 1][0];
    const bf16* Bbuf = &Bs[t & 1][0];
    s16x8 af[4], bfr[4];
#pragma unroll
    for (int m = 0; m < 4; ++m) {
      int r = wm * 64 + m * 16 + la;
      af[m] = *reinterpret_cast<const s16x8*>(Abuf + r * 32 + (q ^ ((r >> 1) & 3)) * 8);
    }
#pragma unroll
    for (int n = 0; n < 4; ++n) {
      int r = wn * 64 + n * 16 + la;
      bfr[n] = *reinterpret_cast<const s16x8*>(Bbuf + r * 32 + (q ^ ((r >> 1) & 3)) * 8);
    }
    __builtin_amdgcn_s_setprio(1);
#pragma unroll
    for (int m = 0; m < 4; ++m)
#pragma unroll
      for (int n = 0; n < 4; ++n)
        acc[m][n] = __builtin_amdgcn_mfma_f32_16x16x32_bf16(bfr[n], af[m], acc[m][n], 0, 0, 0);
    __builtin_amdgcn_s_setprio(0);
  }

  // epilogue: acc[m][n][r] -> C[bm+wm*64+m*16+la][bn+wn*64+n*16+q*4+r]
#pragma unroll
  for (int m = 0; m < 4; ++m) {
    int gm = bm + wm * 64 + m * 16 + la;
#pragma unroll
    for (int n = 0; n < 4; ++n) {
      int gn = bn + wn * 64 + n * 16 + q * 4;
      float4 b4 = *reinterpret_cast<const float4*>(bias + gn);
      float v0 = acc[m][n][0] + b4.x, v1 = acc[m][n][1] + b4.y;
      float v2 = acc[m][n][2] + b4.z, v3 = acc[m][n][3] + b4.w;
      if (RELU) {
        v0 = fmaxf(v0, 0.f); v1 = fmaxf(v1, 0.f);
        v2 = fmaxf(v2, 0.f); v3 = fmaxf(v3, 0.f);
      }
      long idx = coff + (long)gm * ldc + gn;
      if (OUT_BF16) {
        bf16 tmp[4] = {f2bf(v0), f2bf(v1), f2bf(v2), f2bf(v3)};
        __builtin_memcpy((bf16*)Cout + idx, tmp, 8);
      } else {
        float tmp[4] = {v0, v1, v2, v3};
        __builtin_memcpy((float*)Cout + idx, tmp, 16);
      }
    }
  }
}

// ---------------- attention over the expert axis (E=8, H=8, HD=64) ----------
__global__ __launch_bounds__(256) void attn_kernel(const float* __restrict__ q,
                                                   const bf16* __restrict__ kv,
                                                   bf16* __restrict__ ctx,
                                                   const int* __restrict__ eid) {
  int wave = threadIdx.x >> 6, lane = threadIdx.x & 63;
  int n = blockIdx.x * 4 + wave;
  int h = lane >> 3, f = lane & 7;
  int e3 = *eid;
  const bf16* kvn = kv + (long)n * Em * (2 * Dm);
  const float* qh = q + (long)n * Dm + h * 64;
  const bf16* kf = kvn + f * (2 * Dm) + h * 64;
  float s = 0.f;
#pragma unroll
  for (int j = 0; j < 64; j++) s += qh[j] * bf2f(kf[j]);
  s *= 0.125f;
  s += (f <= e3) ? 1.0f : 0.0f;  // torch-faithful ADDITIVE float tril mask
  float mx = s;
#pragma unroll
  for (int d = 1; d < 8; d <<= 1) mx = fmaxf(mx, __shfl_xor(mx, d));
  float ex = expf(s - mx);
  float sm = ex;
#pragma unroll
  for (int d = 1; d < 8; d <<= 1) sm += __shfl_xor(sm, d);
  float at = ex / sm;
  int g = f;
  float acc[8] = {0, 0, 0, 0, 0, 0, 0, 0};
#pragma unroll
  for (int f2 = 0; f2 < 8; f2++) {
    float a = __shfl(at, (h << 3) | f2);
    const bf16* vf = kvn + f2 * (2 * Dm) + Dm + h * 64 + g * 8;
#pragma unroll
    for (int j = 0; j < 8; j++) acc[j] += a * bf2f(vf[j]);
  }
  bf16 tmp[8];
#pragma unroll
  for (int j = 0; j < 8; j++) tmp[j] = f2bf(acc[j]);
  __builtin_memcpy(ctx + (long)n * Dm + h * 64 + g * 8, tmp, 16);
}

extern "C" void kernel_launch(void* const* d_in, const int* in_sizes, int n_in,
                              void* d_out, int out_size, void* d_ws, size_t ws_size,
                              hipStream_t stream) {
  const float* x  = (const float*)d_in[0];
  const float* W1 = (const float*)d_in[1];
  const float* b1 = (const float*)d_in[2];
  const float* W2 = (const float*)d_in[3];
  const float* b2 = (const float*)d_in[4];
  const float* Wq = (const float*)d_in[5];
  const float* bq = (const float*)d_in[6];
  const float* Wk = (const float*)d_in[7];
  const float* bk = (const float*)d_in[8];
  const float* Wv = (const float*)d_in[9];
  const float* bv = (const float*)d_in[10];
  const float* Wo = (const float*)d_in[11];
  const float* bo = (const float*)d_in[12];
  const int* eid  = (const int*)d_in[13];

  char* w = (char*)d_ws;
  auto alloc = [&](size_t bytes) {
    char* p = w;
    w += (bytes + 255) & ~(size_t)255;
    return p;
  };
  bf16* xb   = (bf16*)alloc((size_t)N_TOK * Dm * 2);
  bf16* W1t  = (bf16*)alloc((size_t)Em * Fm * Dm * 2);
  bf16* W2t  = (bf16*)alloc((size_t)Em * Dm * Fm * 2);
  bf16* qw   = (bf16*)alloc((size_t)Dm * Dm * 2);
  bf16* kvw  = (bf16*)alloc((size_t)2 * Dm * Dm * 2);
  bf16* ow   = (bf16*)alloc((size_t)Dm * Dm * 2);
  float* bkv = (float*)alloc((size_t)2 * Dm * 4);
  bf16* hid  = (bf16*)alloc((size_t)Em * N_TOK * Fm * 2);   // 128 MB [e][n][f]
  bf16* eo   = (bf16*)alloc((size_t)N_TOK * Em * Dm * 2);   // [n][e][d]
  bf16* kv   = (bf16*)hid;                                  // alias: [n*E+e][2D]
  float* qb  = (float*)(hid + (size_t)N_TOK * Em * 2 * Dm);
  bf16* ctxb = (bf16*)(qb + (size_t)N_TOK * Dm);

  // ---- converts / transposes (3 launches) ----
  cvt_all<<<3073, 256, 0, stream>>>(x, Wq, Wk, Wv, Wo, bk, bv, xb, qw, kvw, ow, bkv);
  transpose_cvt<<<dim3(Fm / 32, Dm / 32, Em), 256, 0, stream>>>(
      W1, W1t, Dm, Fm, (long)Dm * Fm, (long)Fm * Dm);
  transpose_cvt<<<dim3(Dm / 32, Fm / 32, Em), 256, 0, stream>>>(
      W2, W2t, Fm, Dm, (long)Fm * Dm, (long)Dm * Fm);

  // ---- FFN stage 1: hid[e] = relu(x @ W1[e] + b1[e])  M=4096 N=2048 K=512
  gemm128p<true, true><<<dim3(32, 16, Em), 256, 0, stream>>>(
      xb, W1t, hid, b1, Dm, Dm, Dm, Fm,
      0L, (long)Fm * Dm, (long)N_TOK * Fm, (long)Fm, nullptr, 0);
  // ---- FFN stage 2: eo[n][e][:] = hid[e] @ W2[e] + b2[e]  M=4096 N=512 K=2048
  gemm128p<false, true><<<dim3(32, 4, Em), 256, 0, stream>>>(
      hid, W2t, eo, b2, Fm, Fm, Fm, Em * Dm,
      (long)N_TOK * Fm, (long)Dm * Fm, (long)Dm, (long)Dm, nullptr, 0);
  // ---- K|V for all expert rows: M=32768 N=1024 K=512
  gemm128p<false, true><<<dim3(256, 8, 1), 256, 0, stream>>>(
      eo, kvw, kv, bkv, Dm, Dm, Dm, 2 * Dm,
      0L, 0L, 0L, 0L, nullptr, 0);
  // ---- Q only for expert row e_id: M=4096 N=512 K=512
  gemm128p<false, false><<<dim3(32, 4, 1), 256, 0, stream>>>(
      eo, qw, qb, bq, Dm, Em * Dm, Dm, Dm,
      0L, 0L, 0L, 0L, eid, Dm);
  // ---- attention over experts ----
  attn_kernel<<<N_TOK / 4, 256, 0, stream>>>(qb, kv, ctxb, eid);
  // ---- out projection -> d_out (fp32): M=4096 N=512 K=512
  gemm128p<false, false><<<dim3(32, 4, 1), 256, 0, stream>>>(
      ctxb, ow, (float*)d_out, bo, Dm, Dm, Dm, Dm,
      0L, 0L, 0L, 0L, nullptr, 0);
}

// Round 19
// 284.826 us; speedup vs baseline: 1.1561x; 1.1561x over previous
//
#include <hip/hip_runtime.h>
#include <hip/hip_bf16.h>

typedef __hip_bfloat16 bf16;
typedef __attribute__((ext_vector_type(4))) float f32x4;
typedef __attribute__((ext_vector_type(8))) short s16x8;

#define N_TOK 4096   // B*S
#define Dm    512
#define Fm    2048
#define Em    8

__device__ __forceinline__ float bf2f(bf16 v) { return __bfloat162float(v); }
__device__ __forceinline__ bf16  f2bf(float f) { return __float2bfloat16(f); }

// async global->LDS, 16B per lane; LDS dest is wave-uniform base + lane*16
#define GL16(g, l)                                                              \
  __builtin_amdgcn_global_load_lds(                                             \
      (const __attribute__((address_space(1))) void*)(g),                       \
      (__attribute__((address_space(3))) void*)(l), 16, 0, 0)

// ---- fused convert: x (2048 blks) + 4 DxD weights (1024 blks) + bkv (1) ----
__global__ void cvt_all(const float* __restrict__ x, const float* __restrict__ Wq,
                        const float* __restrict__ Wk, const float* __restrict__ Wv,
                        const float* __restrict__ Wo, const float* __restrict__ bk,
                        const float* __restrict__ bv, bf16* __restrict__ xb,
                        bf16* __restrict__ qw, bf16* __restrict__ kvw,
                        bf16* __restrict__ ow, float* __restrict__ bkv) {
  int b = blockIdx.x;
  if (b < 2048) {  // x: 4096*512/4 = 524288 float4
    int i = b * 256 + threadIdx.x;
    float4 v = reinterpret_cast<const float4*>(x)[i];
    bf16 tmp[4] = {f2bf(v.x), f2bf(v.y), f2bf(v.z), f2bf(v.w)};
    __builtin_memcpy(xb + (size_t)i * 4, tmp, 8);
  } else if (b < 3072) {
    int bb = b - 2048;
    int which = bb >> 8;
    int i = (bb & 255) * 256 + threadIdx.x;  // 65536 float4 per matrix
    const float* src = which == 0 ? Wq : which == 1 ? Wk : which == 2 ? Wv : Wo;
    bf16* dst = which == 0 ? qw : which == 1 ? kvw
              : which == 2 ? (kvw + (size_t)Dm * Dm) : ow;
    float4 v = reinterpret_cast<const float4*>(src)[i];
    bf16 tmp[4] = {f2bf(v.x), f2bf(v.y), f2bf(v.z), f2bf(v.w)};
    __builtin_memcpy(dst + (size_t)i * 4, tmp, 8);
  } else {
    for (int j = threadIdx.x; j < Dm; j += 256) {
      bkv[j] = bk[j];
      bkv[Dm + j] = bv[j];
    }
  }
}

// --- fused fp32->bf16 transpose of W1 AND W2 (one launch, grid 1024 x 16) ----
// y: 0..7 -> W1 expert y ([Dm][Fm] -> [Fm][Dm]); 8..15 -> W2 expert y-8
// ([Fm][Dm] -> [Dm][Fm]). Both have 1024 32x32 tiles per (matrix, expert).
__global__ void transpose_all(const float* __restrict__ W1, const float* __restrict__ W2,
                              bf16* __restrict__ W1t, bf16* __restrict__ W2t) {
  int y = blockIdx.y;
  int which = y >> 3, e = y & 7;
  const float* in;
  bf16* out;
  int R, C, cx, cy;
  if (which == 0) {
    in = W1 + (long)e * Dm * Fm; out = W1t + (long)e * Fm * Dm;
    R = Dm; C = Fm; cx = blockIdx.x & 63; cy = blockIdx.x >> 6;
  } else {
    in = W2 + (long)e * Fm * Dm; out = W2t + (long)e * Dm * Fm;
    R = Fm; C = Dm; cx = blockIdx.x & 15; cy = blockIdx.x >> 4;
  }
  __shared__ float t[32][33];
  int tid = threadIdx.x;
  int col = tid & 31, row8 = tid >> 5;
  int c0 = cx * 32, r0 = cy * 32;
#pragma unroll
  for (int i = 0; i < 4; ++i)
    t[row8 + i * 8][col] = in[(long)(r0 + row8 + i * 8) * C + c0 + col];
  __syncthreads();
  int cc = tid >> 3, rb = (tid & 7) * 4;  // out[c0+cc][r0+rb .. +4]
  bf16 tmp[4];
#pragma unroll
  for (int k = 0; k < 4; ++k) tmp[k] = f2bf(t[rb + k][cc]);
  __builtin_memcpy(out + (long)(c0 + cc) * R + r0 + rb, tmp, 8);
}

// ======== 128x128 BK=64 bf16 GEMM (r10/r17 champion, verbatim) ===============
// 2-barrier lockstep drain: measured optimum across 9 structures (r1-r18).
template <bool RELU, bool OUT_BF16>
__global__ __launch_bounds__(256, 4) void gemm128(
    const bf16* __restrict__ A, const bf16* __restrict__ Bt, void* __restrict__ Cout,
    const float* __restrict__ bias, int K, int lda, int ldb, int ldc,
    long abs_, long bbs, long cbs, long biasbs,
    const int* __restrict__ eid, int eid_scale) {
  __shared__ bf16 As[128 * 64];
  __shared__ bf16 Bs[128 * 64];

  int e  = blockIdx.z;
  int bm = blockIdx.x * 128, bn = blockIdx.y * 128;

  A    += (long)e * abs_;
  Bt   += (long)e * bbs;
  bias += (long)e * biasbs;
  long coff = (long)e * cbs;
  if (eid) A += (long)(*eid) * eid_scale;

  int tid = threadIdx.x, wv = tid >> 6, lane = tid & 63;
  int wm = wv >> 1, wn = wv & 1;

  const bf16* Ab = A + (long)bm * lda;
  const bf16* Bb = Bt + (long)bn * ldb;

  f32x4 acc[4][4] = {};
  int la = lane & 15, q = lane >> 4;
  int srow_lo = lane >> 3;

  for (int k0 = 0; k0 < K; k0 += 64) {
    __syncthreads();
#pragma unroll
    for (int j = 0; j < 4; ++j) {
      int r = (wv * 4 + j) * 8 + srow_lo;
      int c = (lane & 7) ^ (r & 7);
      GL16(Ab + (long)r * lda + k0 + c * 8, As + (wv * 4 + j) * 512);
      GL16(Bb + (long)r * ldb + k0 + c * 8, Bs + (wv * 4 + j) * 512);
    }
    __syncthreads();

#pragma unroll
    for (int kk = 0; kk < 2; ++kk) {
      int ps = (kk * 4 + q) ^ (la & 7);
      s16x8 af[4], bfr[4];
#pragma unroll
      for (int m = 0; m < 4; ++m)
        af[m] = *reinterpret_cast<const s16x8*>(As + (wm * 64 + m * 16 + la) * 64 + ps * 8);
#pragma unroll
      for (int n = 0; n < 4; ++n)
        bfr[n] = *reinterpret_cast<const s16x8*>(Bs + (wn * 64 + n * 16 + la) * 64 + ps * 8);
#pragma unroll
      for (int m = 0; m < 4; ++m)
#pragma unroll
        for (int n = 0; n < 4; ++n)
          acc[m][n] = __builtin_amdgcn_mfma_f32_16x16x32_bf16(bfr[n], af[m], acc[m][n], 0, 0, 0);
    }
  }

#pragma unroll
  for (int m = 0; m < 4; ++m) {
    int gm = bm + wm * 64 + m * 16 + la;
#pragma unroll
    for (int n = 0; n < 4; ++n) {
      int gn = bn + wn * 64 + n * 16 + q * 4;
      float4 b4 = *reinterpret_cast<const float4*>(bias + gn);
      float v0 = acc[m][n][0] + b4.x, v1 = acc[m][n][1] + b4.y;
      float v2 = acc[m][n][2] + b4.z, v3 = acc[m][n][3] + b4.w;
      if (RELU) {
        v0 = fmaxf(v0, 0.f); v1 = fmaxf(v1, 0.f);
        v2 = fmaxf(v2, 0.f); v3 = fmaxf(v3, 0.f);
      }
      long idx = coff + (long)gm * ldc + gn;
      if (OUT_BF16) {
        bf16 tmp[4] = {f2bf(v0), f2bf(v1), f2bf(v2), f2bf(v3)};
        __builtin_memcpy((bf16*)Cout + idx, tmp, 8);
      } else {
        float tmp[4] = {v0, v1, v2, v3};
        __builtin_memcpy((float*)Cout + idx, tmp, 16);
      }
    }
  }
}

// ==== fused KV + Q GEMM (r19): flat grid, blocks [0,2048)=KV, [2048,2176)=Q ==
// Both K=512, same champion body. KV: A=eo [32768][512], B=kvw [1024][512],
// C=kv bf16 ldc=1024. Q: A=eo+eid*512 lda=4096, B=qw, C=qb fp32 ldc=512.
// Q's 128 blocks co-reside with KV's -> Q's ~6us tail is absorbed.
__global__ __launch_bounds__(256, 4) void gemm_kvq(
    const bf16* __restrict__ eo, const bf16* __restrict__ kvw,
    bf16* __restrict__ kvout, const float* __restrict__ bkv,
    const bf16* __restrict__ qw, float* __restrict__ qb,
    const float* __restrict__ bq, const int* __restrict__ eid) {
  __shared__ bf16 As[128 * 64];
  __shared__ bf16 Bs[128 * 64];

  int b = blockIdx.x;
  bool qpath = (b >= 2048);
  const bf16* A;
  const bf16* Bt;
  const float* bias;
  int bm, bn, lda, ldb, ldc;
  if (!qpath) {
    bm = (b & 255) * 128; bn = (b >> 8) * 128;
    A = eo; Bt = kvw; bias = bkv; lda = Dm; ldb = Dm; ldc = 2 * Dm;
  } else {
    int bb = b - 2048;
    bm = (bb & 31) * 128; bn = (bb >> 5) * 128;
    A = eo + (long)(*eid) * Dm; Bt = qw; bias = bq;
    lda = Em * Dm; ldb = Dm; ldc = Dm;
  }

  int tid = threadIdx.x, wv = tid >> 6, lane = tid & 63;
  int wm = wv >> 1, wn = wv & 1;

  const bf16* Ab = A + (long)bm * lda;
  const bf16* Bb = Bt + (long)bn * ldb;

  f32x4 acc[4][4] = {};
  int la = lane & 15, q = lane >> 4;
  int srow_lo = lane >> 3;

  for (int k0 = 0; k0 < Dm; k0 += 64) {
    __syncthreads();
#pragma unroll
    for (int j = 0; j < 4; ++j) {
      int r = (wv * 4 + j) * 8 + srow_lo;
      int c = (lane & 7) ^ (r & 7);
      GL16(Ab + (long)r * lda + k0 + c * 8, As + (wv * 4 + j) * 512);
      GL16(Bb + (long)r * ldb + k0 + c * 8, Bs + (wv * 4 + j) * 512);
    }
    __syncthreads();

#pragma unroll
    for (int kk = 0; kk < 2; ++kk) {
      int ps = (kk * 4 + q) ^ (la & 7);
      s16x8 af[4], bfr[4];
#pragma unroll
      for (int m = 0; m < 4; ++m)
        af[m] = *reinterpret_cast<const s16x8*>(As + (wm * 64 + m * 16 + la) * 64 + ps * 8);
#pragma unroll
      for (int n = 0; n < 4; ++n)
        bfr[n] = *reinterpret_cast<const s16x8*>(Bs + (wn * 64 + n * 16 + la) * 64 + ps * 8);
#pragma unroll
      for (int m = 0; m < 4; ++m)
#pragma unroll
        for (int n = 0; n < 4; ++n)
          acc[m][n] = __builtin_amdgcn_mfma_f32_16x16x32_bf16(bfr[n], af[m], acc[m][n], 0, 0, 0);
    }
  }

#pragma unroll
  for (int m = 0; m < 4; ++m) {
    int gm = bm + wm * 64 + m * 16 + la;
#pragma unroll
    for (int n = 0; n < 4; ++n) {
      int gn = bn + wn * 64 + n * 16 + q * 4;
      float4 b4 = *reinterpret_cast<const float4*>(bias + gn);
      float v0 = acc[m][n][0] + b4.x, v1 = acc[m][n][1] + b4.y;
      float v2 = acc[m][n][2] + b4.z, v3 = acc[m][n][3] + b4.w;
      long idx = (long)gm * ldc + gn;
      if (!qpath) {
        bf16 tmp[4] = {f2bf(v0), f2bf(v1), f2bf(v2), f2bf(v3)};
        __builtin_memcpy(kvout + idx, tmp, 8);
      } else {
        float tmp[4] = {v0, v1, v2, v3};
        __builtin_memcpy(qb + idx, tmp, 16);
      }
    }
  }
}

// ---------------- attention over the expert axis (E=8, H=8, HD=64) ----------
__global__ __launch_bounds__(256) void attn_kernel(const float* __restrict__ q,
                                                   const bf16* __restrict__ kv,
                                                   bf16* __restrict__ ctx,
                                                   const int* __restrict__ eid) {
  int wave = threadIdx.x >> 6, lane = threadIdx.x & 63;
  int n = blockIdx.x * 4 + wave;
  int h = lane >> 3, f = lane & 7;
  int e3 = *eid;
  const bf16* kvn = kv + (long)n * Em * (2 * Dm);
  const float* qh = q + (long)n * Dm + h * 64;
  const bf16* kf = kvn + f * (2 * Dm) + h * 64;
  float s = 0.f;
#pragma unroll
  for (int j = 0; j < 64; j++) s += qh[j] * bf2f(kf[j]);
  s *= 0.125f;
  s += (f <= e3) ? 1.0f : 0.0f;  // torch-faithful ADDITIVE float tril mask
  float mx = s;
#pragma unroll
  for (int d = 1; d < 8; d <<= 1) mx = fmaxf(mx, __shfl_xor(mx, d));
  float ex = expf(s - mx);
  float sm = ex;
#pragma unroll
  for (int d = 1; d < 8; d <<= 1) sm += __shfl_xor(sm, d);
  float at = ex / sm;
  int g = f;
  float acc[8] = {0, 0, 0, 0, 0, 0, 0, 0};
#pragma unroll
  for (int f2 = 0; f2 < 8; f2++) {
    float a = __shfl(at, (h << 3) | f2);
    const bf16* vf = kvn + f2 * (2 * Dm) + Dm + h * 64 + g * 8;
#pragma unroll
    for (int j = 0; j < 8; j++) acc[j] += a * bf2f(vf[j]);
  }
  bf16 tmp[8];
#pragma unroll
  for (int j = 0; j < 8; j++) tmp[j] = f2bf(acc[j]);
  __builtin_memcpy(ctx + (long)n * Dm + h * 64 + g * 8, tmp, 16);
}

extern "C" void kernel_launch(void* const* d_in, const int* in_sizes, int n_in,
                              void* d_out, int out_size, void* d_ws, size_t ws_size,
                              hipStream_t stream) {
  const float* x  = (const float*)d_in[0];
  const float* W1 = (const float*)d_in[1];
  const float* b1 = (const float*)d_in[2];
  const float* W2 = (const float*)d_in[3];
  const float* b2 = (const float*)d_in[4];
  const float* Wq = (const float*)d_in[5];
  const float* bq = (const float*)d_in[6];
  const float* Wk = (const float*)d_in[7];
  const float* bk = (const float*)d_in[8];
  const float* Wv = (const float*)d_in[9];
  const float* bv = (const float*)d_in[10];
  const float* Wo = (const float*)d_in[11];
  const float* bo = (const float*)d_in[12];
  const int* eid  = (const int*)d_in[13];

  char* w = (char*)d_ws;
  auto alloc = [&](size_t bytes) {
    char* p = w;
    w += (bytes + 255) & ~(size_t)255;
    return p;
  };
  bf16* xb   = (bf16*)alloc((size_t)N_TOK * Dm * 2);
  bf16* W1t  = (bf16*)alloc((size_t)Em * Fm * Dm * 2);
  bf16* W2t  = (bf16*)alloc((size_t)Em * Dm * Fm * 2);
  bf16* qw   = (bf16*)alloc((size_t)Dm * Dm * 2);
  bf16* kvw  = (bf16*)alloc((size_t)2 * Dm * Dm * 2);
  bf16* ow   = (bf16*)alloc((size_t)Dm * Dm * 2);
  float* bkv = (float*)alloc((size_t)2 * Dm * 4);
  bf16* hid  = (bf16*)alloc((size_t)Em * N_TOK * Fm * 2);   // 128 MB [e][n][f]
  bf16* eo   = (bf16*)alloc((size_t)N_TOK * Em * Dm * 2);   // [n][e][d]
  bf16* kv   = (bf16*)hid;                                  // alias: [n*E+e][2D]
  float* qb  = (float*)(hid + (size_t)N_TOK * Em * 2 * Dm);
  bf16* ctxb = (bf16*)(qb + (size_t)N_TOK * Dm);

  // ---- converts / transposes (2 launches) ----
  cvt_all<<<3073, 256, 0, stream>>>(x, Wq, Wk, Wv, Wo, bk, bv, xb, qw, kvw, ow, bkv);
  transpose_all<<<dim3(1024, 16), 256, 0, stream>>>(W1, W2, W1t, W2t);

  // ---- FFN stage 1: hid[e] = relu(x @ W1[e] + b1[e])  M=4096 N=2048 K=512
  gemm128<true, true><<<dim3(32, 16, Em), 256, 0, stream>>>(
      xb, W1t, hid, b1, Dm, Dm, Dm, Fm,
      0L, (long)Fm * Dm, (long)N_TOK * Fm, (long)Fm, nullptr, 0);
  // ---- FFN stage 2: eo[n][e][:] = hid[e] @ W2[e] + b2[e]  M=4096 N=512 K=2048
  gemm128<false, true><<<dim3(32, 4, Em), 256, 0, stream>>>(
      hid, W2t, eo, b2, Fm, Fm, Fm, Em * Dm,
      (long)N_TOK * Fm, (long)Dm * Fm, (long)Dm, (long)Dm, nullptr, 0);
  // ---- fused K|V (all expert rows) + Q (expert e_id): 2176 blocks ----
  gemm_kvq<<<2176, 256, 0, stream>>>(eo, kvw, kv, bkv, qw, qb, bq, eid);
  // ---- attention over experts ----
  attn_kernel<<<N_TOK / 4, 256, 0, stream>>>(qb, kv, ctxb, eid);
  // ---- out projection -> d_out (fp32): M=4096 N=512 K=512
  gemm128<false, false><<<dim3(32, 4, 1), 256, 0, stream>>>(
      ctxb, ow, (float*)d_out, bo, Dm, Dm, Dm, Dm,
      0L, 0L, 0L, 0L, nullptr, 0);
}